// Round 3
// baseline (504.525 us; speedup 1.0000x reference)
//
#include <hip/hip_runtime.h>
#include <hip/hip_bf16.h>

// Problem constants (from reference): B=64, C=256, H=64, W=64, EMB=512, NH=4, HD=64.
// Key algebraic fact: K/V sequence length is 1 -> softmax over a size-1 axis == 1.0
// identically, so q / layernorm / wk are dead code. The whole block reduces to:
//   v_in[b]     = cond_emb[b] @ kv_w[C:2C].T + kv_b[C:2C]          (64 x 256)
//   v_row[b]    = v_in[b] @ wv.T + bv,  wv = in_proj_w[2C:3C]      (64 x 256)
//   attn_out[b] = v_row[b] @ out_w.T + out_b                       (64 x 256)
//   y[b,c,h,w]  = x[b,c,h,w] + attn_out[b,c]
// Structural floor: elementwise pass reads+writes 2 * 268 MB -> ~85 us at 6.3 TB/s.
// Timed graph also contains ~2x 1GiB harness poison fills (~325 us) we cannot touch.

#define Bc 64
#define Cc 256
#define EMBc 512
#define HWc 4096

// Native vector type: __builtin_nontemporal_store rejects HIP_vector_type float4.
typedef float v4f __attribute__((ext_vector_type(4)));

// One block per batch element, 512 threads: 2-way split-K on every GEMV stage.
// Rationale: at 256 threads this kernel ran 1 wave/SIMD (no TLP); every stage's
// dependent-load chain was exposed. 512 threads halves the chain AND doubles
// waves/SIMD.
__global__ __launch_bounds__(512) void attn_vec_kernel(
    const float* __restrict__ cond_emb,   // (B, EMB)
    const float* __restrict__ in_proj_w,  // (3C, C)
    const float* __restrict__ in_proj_b,  // (3C,)
    const float* __restrict__ out_w,      // (C, C)
    const float* __restrict__ out_b,      // (C,)
    const float* __restrict__ kv_w,       // (2C, EMB)
    const float* __restrict__ kv_b,       // (2C,)
    float* __restrict__ attn_out)         // (B, C) scratch
{
    __shared__ float4 s_cond[EMBc / 4];   // 128 float4 = 2 KB
    __shared__ float  s_part[512];        // split-K partials
    __shared__ float4 s_vin[Cc / 4];      // 64 float4
    __shared__ float4 s_vrow[Cc / 4];     // 64 float4

    const int b   = blockIdx.x;
    const int tid = threadIdx.x;
    const int o   = tid & 255;            // output element
    const int h   = tid >> 8;             // K-half: 0 or 1

    // stage cond_emb row (512 floats = 128 float4)
    if (tid < EMBc / 4)
        s_cond[tid] = ((const float4*)(cond_emb + (size_t)b * EMBc))[tid];
    __syncthreads();

    // stage 1: v_in[o] = cond . kv_w[C+o, :] + kv_b[C+o]   (dot-512, split 2x256)
    {
        const float4* wrow = (const float4*)(kv_w + (size_t)(Cc + o) * EMBc) + h * 64;
        const float4* crow = s_cond + h * 64;
        float acc = 0.f;
        #pragma unroll 8
        for (int e = 0; e < 64; ++e) {
            float4 w = wrow[e], c = crow[e];
            acc += w.x * c.x + w.y * c.y + w.z * c.z + w.w * c.w;
        }
        s_part[tid] = acc;
    }
    __syncthreads();
    if (tid < 256)
        ((float*)s_vin)[tid] = s_part[tid] + s_part[tid + 256] + kv_b[Cc + tid];
    __syncthreads();

    // stage 2: v_row[o] = v_in . wv[o, :] + bv[o]   (dot-256, split 2x128)
    {
        const float4* wrow = (const float4*)(in_proj_w + (size_t)(2 * Cc + o) * Cc) + h * 32;
        const float4* crow = s_vin + h * 32;
        float acc = 0.f;
        #pragma unroll 8
        for (int j = 0; j < 32; ++j) {
            float4 w = wrow[j], c = crow[j];
            acc += w.x * c.x + w.y * c.y + w.z * c.z + w.w * c.w;
        }
        s_part[tid] = acc;
    }
    __syncthreads();
    if (tid < 256)
        ((float*)s_vrow)[tid] = s_part[tid] + s_part[tid + 256] + in_proj_b[2 * Cc + tid];
    __syncthreads();

    // stage 3: attn_out[b,o] = v_row . out_w[o, :] + out_b[o]   (dot-256, split 2x128)
    {
        const float4* wrow = (const float4*)(out_w + (size_t)o * Cc) + h * 32;
        const float4* crow = s_vrow + h * 32;
        float acc = 0.f;
        #pragma unroll 8
        for (int i = 0; i < 32; ++i) {
            float4 w = wrow[i], c = crow[i];
            acc += w.x * c.x + w.y * c.y + w.z * c.z + w.w * c.w;
        }
        s_part[tid] = acc;
    }
    __syncthreads();
    if (tid < 256)
        attn_out[(size_t)b * Cc + tid] = s_part[tid] + s_part[tid + 256] + out_b[tid];
}

// y = x + attn_out[b,c].
// Grid-stride redesign: 4096 blocks x 256 threads x 16 float4/thread.
// Each block owns exactly 4 consecutive (b,c) planes (4 x 1024 float4), so the
// 4 broadcast addends are block-uniform (scalar loads, no VALU waste), and each
// thread keeps ~16 loads in flight instead of 1 (old version: 65,536 blocks of
// 4 KB each -> per-block launch/retire overhead on a BW-bound kernel).
__global__ __launch_bounds__(256) void add_broadcast_kernel(
    const v4f* __restrict__ x4,
    const float* __restrict__ attn_out,
    v4f* __restrict__ y4)
{
    const size_t base = (size_t)blockIdx.x * 4096;   // float4 units, 4 planes
    const int    bc0  = (int)(blockIdx.x * 4);       // first plane index

    float a[4];
    #pragma unroll
    for (int i = 0; i < 4; ++i)
        a[i] = attn_out[bc0 + i];                    // block-uniform -> s_load

    #pragma unroll
    for (int i = 0; i < 16; ++i) {
        const size_t idx = base + (size_t)i * 256 + threadIdx.x;
        v4f v = x4[idx];
        const float ai = a[i >> 2];                  // plane = i/4, compile-time
        v += ai;                                     // ext-vector splat add
        __builtin_nontemporal_store(v, &y4[idx]);    // y never re-read
    }
}

extern "C" void kernel_launch(void* const* d_in, const int* in_sizes, int n_in,
                              void* d_out, int out_size, void* d_ws, size_t ws_size,
                              hipStream_t stream) {
    const float* x         = (const float*)d_in[0];
    const float* cond_emb  = (const float*)d_in[1];
    // d_in[2] ln_gamma, d_in[3] ln_beta: dead (only feed q, which softmax erases)
    const float* in_proj_w = (const float*)d_in[4];
    const float* in_proj_b = (const float*)d_in[5];
    const float* out_w     = (const float*)d_in[6];
    const float* out_b     = (const float*)d_in[7];
    const float* kv_w      = (const float*)d_in[8];
    const float* kv_b      = (const float*)d_in[9];

    float* attn_out = (float*)d_ws;  // 64*256 floats = 64 KB
    float* y        = (float*)d_out;

    attn_vec_kernel<<<Bc, 512, 0, stream>>>(cond_emb, in_proj_w, in_proj_b,
                                            out_w, out_b, kv_w, kv_b, attn_out);

    // 64*256*4096 floats = 16,777,216 float4; 4096 float4 per block.
    add_broadcast_kernel<<<4096, 256, 0, stream>>>(
        (const v4f*)x, attn_out, (v4f*)y);
}

// Round 4
// 476.849 us; speedup vs baseline: 1.0580x; 1.0580x over previous
//
#include <hip/hip_runtime.h>
#include <hip/hip_bf16.h>

// Problem constants (from reference): B=64, C=256, H=64, W=64, EMB=512, NH=4, HD=64.
// Key algebraic fact: K/V sequence length is 1 -> softmax over a size-1 axis == 1.0
// identically, so q / layernorm / wk are dead code. The whole block reduces to:
//   v_in[b]     = cond_emb[b] @ kv_w[C:2C].T + kv_b[C:2C]          (64 x 256)
//   v_row[b]    = v_in[b] @ wv.T + bv,  wv = in_proj_w[2C:3C]      (64 x 256)
//   attn_out[b] = v_row[b] @ out_w.T + out_b                       (64 x 256)
//   y[b,c,h,w]  = x[b,c,h,w] + attn_out[b,c]
// Structural floor: elementwise pass reads+writes 2 * 268 MB -> ~85 us at 6.3 TB/s.
// Timed graph also contains ~2x 1GiB harness poison fills (~325 us) we cannot touch.
//
// History:
//  R0 (463 us): add = 65,536 blocks x 1 float4/thread  -> ~130 us (4.1 TB/s demand)
//  R3 (504 us): add = 4,096 blocks x 16 float4 + nt    -> 167 us, VGPR=32 (no
//               pipelining materialized), 2.4 TB/s HBM-side. nt store + register-
//               starved unroll = regression. REVERTED.
//  R4: one block per (b,c) plane, 4 float4/thread via explicit named registers
//      (4 independent loads genuinely in flight at ~24 VGPR), plain stores.

#define Bc 64
#define Cc 256
#define EMBc 512
#define HWc 4096

typedef float v4f __attribute__((ext_vector_type(4)));

// One block per batch element, 512 threads: 2-way split-K on every GEMV stage.
__global__ __launch_bounds__(512) void attn_vec_kernel(
    const float* __restrict__ cond_emb,   // (B, EMB)
    const float* __restrict__ in_proj_w,  // (3C, C)
    const float* __restrict__ in_proj_b,  // (3C,)
    const float* __restrict__ out_w,      // (C, C)
    const float* __restrict__ out_b,      // (C,)
    const float* __restrict__ kv_w,       // (2C, EMB)
    const float* __restrict__ kv_b,       // (2C,)
    float* __restrict__ attn_out)         // (B, C) scratch
{
    __shared__ float4 s_cond[EMBc / 4];   // 128 float4 = 2 KB
    __shared__ float  s_part[512];        // split-K partials
    __shared__ float4 s_vin[Cc / 4];      // 64 float4
    __shared__ float4 s_vrow[Cc / 4];     // 64 float4

    const int b   = blockIdx.x;
    const int tid = threadIdx.x;
    const int o   = tid & 255;            // output element
    const int h   = tid >> 8;             // K-half: 0 or 1

    // stage cond_emb row (512 floats = 128 float4)
    if (tid < EMBc / 4)
        s_cond[tid] = ((const float4*)(cond_emb + (size_t)b * EMBc))[tid];
    __syncthreads();

    // stage 1: v_in[o] = cond . kv_w[C+o, :] + kv_b[C+o]   (dot-512, split 2x256)
    {
        const float4* wrow = (const float4*)(kv_w + (size_t)(Cc + o) * EMBc) + h * 64;
        const float4* crow = s_cond + h * 64;
        float acc = 0.f;
        #pragma unroll 8
        for (int e = 0; e < 64; ++e) {
            float4 w = wrow[e], c = crow[e];
            acc += w.x * c.x + w.y * c.y + w.z * c.z + w.w * c.w;
        }
        s_part[tid] = acc;
    }
    __syncthreads();
    if (tid < 256)
        ((float*)s_vin)[tid] = s_part[tid] + s_part[tid + 256] + kv_b[Cc + tid];
    __syncthreads();

    // stage 2: v_row[o] = v_in . wv[o, :] + bv[o]   (dot-256, split 2x128)
    {
        const float4* wrow = (const float4*)(in_proj_w + (size_t)(2 * Cc + o) * Cc) + h * 32;
        const float4* crow = s_vin + h * 32;
        float acc = 0.f;
        #pragma unroll 8
        for (int j = 0; j < 32; ++j) {
            float4 w = wrow[j], c = crow[j];
            acc += w.x * c.x + w.y * c.y + w.z * c.z + w.w * c.w;
        }
        s_part[tid] = acc;
    }
    __syncthreads();
    if (tid < 256)
        ((float*)s_vrow)[tid] = s_part[tid] + s_part[tid + 256] + in_proj_b[2 * Cc + tid];
    __syncthreads();

    // stage 3: attn_out[b,o] = v_row . out_w[o, :] + out_b[o]   (dot-256, split 2x128)
    {
        const float4* wrow = (const float4*)(out_w + (size_t)o * Cc) + h * 32;
        const float4* crow = s_vrow + h * 32;
        float acc = 0.f;
        #pragma unroll 8
        for (int i = 0; i < 32; ++i) {
            float4 w = wrow[i], c = crow[i];
            acc += w.x * c.x + w.y * c.y + w.z * c.z + w.w * c.w;
        }
        s_part[tid] = acc;
    }
    __syncthreads();
    if (tid < 256)
        attn_out[(size_t)b * Cc + tid] = s_part[tid] + s_part[tid + 256] + out_b[tid];
}

// y = x + attn_out[b,c].
// One block per (b,c) plane: 16,384 blocks x 256 threads x 4 float4/thread.
// The broadcast addend is a single block-uniform scalar (s_load). The 4 loads
// are explicit named registers issued back-to-back -> 4 independent loads in
// flight at ~24 VGPR (R3's 16-deep unroll collapsed to VGPR=32 and serialized).
// Plain stores: R3's nontemporal stores coincided with a 2.4 TB/s HBM-side
// throttle while the harness's own fill does 6.6 TB/s with normal stores.
__global__ __launch_bounds__(256) void add_broadcast_kernel(
    const v4f* __restrict__ x4,
    const float* __restrict__ attn_out,
    v4f* __restrict__ y4)
{
    const int    bc   = (int)blockIdx.x;             // plane index, block-uniform
    const float  a    = attn_out[bc];                // s_load broadcast
    const size_t base = (size_t)bc * 1024 + threadIdx.x;

    v4f r0 = x4[base];
    v4f r1 = x4[base + 256];
    v4f r2 = x4[base + 512];
    v4f r3 = x4[base + 768];

    y4[base]       = r0 + a;
    y4[base + 256] = r1 + a;
    y4[base + 512] = r2 + a;
    y4[base + 768] = r3 + a;
}

extern "C" void kernel_launch(void* const* d_in, const int* in_sizes, int n_in,
                              void* d_out, int out_size, void* d_ws, size_t ws_size,
                              hipStream_t stream) {
    const float* x         = (const float*)d_in[0];
    const float* cond_emb  = (const float*)d_in[1];
    // d_in[2] ln_gamma, d_in[3] ln_beta: dead (only feed q, which softmax erases)
    const float* in_proj_w = (const float*)d_in[4];
    const float* in_proj_b = (const float*)d_in[5];
    const float* out_w     = (const float*)d_in[6];
    const float* out_b     = (const float*)d_in[7];
    const float* kv_w      = (const float*)d_in[8];
    const float* kv_b      = (const float*)d_in[9];

    float* attn_out = (float*)d_ws;  // 64*256 floats = 64 KB
    float* y        = (float*)d_out;

    attn_vec_kernel<<<Bc, 512, 0, stream>>>(cond_emb, in_proj_w, in_proj_b,
                                            out_w, out_b, kv_w, kv_b, attn_out);

    // 64*256 = 16,384 (b,c) planes; one block each (1024 float4 per plane).
    add_broadcast_kernel<<<Bc * Cc, 256, 0, stream>>>(
        (const v4f*)x, attn_out, (v4f*)y);
}